// Round 8
// baseline (336.384 us; speedup 1.0000x reference)
//
#include <hip/hip_runtime.h>
#include <cstddef>

constexpr int B = 8, L = 999, C = 768, C2 = 384, H = 8, HD = 48;
constexpr int KVL = 1000;                            // kv buffer row stride (16B-aligned rows)
constexpr float ATT_SCALE = 0.14433756729740644f;   // 48^-0.5
constexpr float LOG2E = 1.4426950408889634f;
constexpr float BN_EPS = 1e-5f;
constexpr float INV_N = 1.0f / (8.0f * 999.0f);     // 1/(B*L)

constexpr size_t SZ_XT   = (size_t)B * C * L;       // 6,137,856
constexpr size_t SZ_HALF = (size_t)B * C2 * L;      // 3,068,928 = 4 * (B*96*L)
constexpr size_t OFF_XT  = 0;                       // xt fp32 [c][l], later t1 [l][C]
constexpr size_t OFF_XT2 = SZ_XT;                   // xt2 fp32 [c][l] (lower half only)
constexpr size_t OFF_KV  = 2 * SZ_XT;               // kv bf16 [o][KVL] -> c1part fp32 -> y3 fp32
constexpr size_t OFF_AX  = 3 * SZ_XT;               // x2bf+kvinbf (bf16 [l][c]) -> attnout fp32 (live to end)
constexpr size_t OFF_Q   = 3 * SZ_XT + SZ_HALF;     // q bf16 [o][l], later h2 fp32 [l][96]
constexpr size_t OFF_SM  = 3 * SZ_XT + SZ_HALF + SZ_HALF / 2;

// small-region offsets (floats, relative to OFF_SM)
constexpr size_t SM_POOLED = 0;       // B*C2*3
constexpr size_t SM_XM     = 9216;    // B*C2
constexpr size_t SM_H1     = 12288;   // B*4*96
constexpr size_t SM_WDYN   = 15360;   // B*C2*3
constexpr size_t SM_BDYN   = 24576;   // B*C2
constexpr size_t SM_SUM1   = 27648;   // 768
constexpr size_t SM_SQ1    = 28416;
constexpr size_t SM_CB1    = 30720;   // 96
constexpr size_t SM_SUM2   = 30816;   // 96
constexpr size_t SM_SQ2    = 30912;
constexpr size_t SM_CB2    = 31200;   // 768
constexpr size_t SM_SUM3   = 31968;
constexpr size_t SM_SQ3    = 32736;
constexpr size_t SM_ZEND   = 33504;   // memset end
constexpr size_t SM_END    = 35040;
// bf16 weight copies (float-slot offsets relative to OFF_SM)
constexpr size_t SM_WQ  = SM_END;
constexpr size_t SM_WKV = SM_WQ + 73728;
constexpr size_t SM_WC1 = SM_WKV + 147456;
constexpr size_t SM_WC2 = SM_WC1 + 36864;

typedef __attribute__((ext_vector_type(8))) short bf16x8;
typedef __attribute__((ext_vector_type(4))) float floatx4;

__device__ __forceinline__ float gelu_f(float x) {
  return 0.5f * x * (1.0f + erff(x * 0.70710678118654752f));
}

__device__ __forceinline__ float wave_sum(float v) {
  #pragma unroll
  for (int off = 32; off > 0; off >>= 1) v += __shfl_down(v, off, 64);
  return v;
}

__device__ __forceinline__ short f2bf(float f) {
  union { float f; unsigned u; } x; x.f = f;
  unsigned r = x.u + 0x7FFFu + ((x.u >> 16) & 1u);
  return (short)(r >> 16);
}

// pack 8 f32 -> bf16x8 via v_cvt_pk_bf16_f32 (RNE, same rounding as f2bf)
__device__ __forceinline__ bf16x8 pack8(const float* p) {
  union { unsigned u[4]; bf16x8 v; } r;
  asm("v_cvt_pk_bf16_f32 %0, %1, %2" : "=v"(r.u[0]) : "v"(p[0]), "v"(p[1]));
  asm("v_cvt_pk_bf16_f32 %0, %1, %2" : "=v"(r.u[1]) : "v"(p[2]), "v"(p[3]));
  asm("v_cvt_pk_bf16_f32 %0, %1, %2" : "=v"(r.u[2]) : "v"(p[4]), "v"(p[5]));
  asm("v_cvt_pk_bf16_f32 %0, %1, %2" : "=v"(r.u[3]) : "v"(p[6]), "v"(p[7]));
  return r.v;
}

__device__ __forceinline__ float exp2_hw(float x) {
  float r;
  asm("v_exp_f32 %0, %1" : "=v"(r) : "v"(x));
  return r;
}

// BN inline: same fp32 expression as old k_bnfin -> bitwise identical
#define BNA(x, su, qq, gg) { float m_ = (su) * INV_N; float v_ = (qq) * INV_N - m_ * m_; \
  float sc_ = (gg) * rsqrtf(v_ + BN_EPS); (x) = ((x) - m_) * sc_; }

// ---------------- fused prep (weights bf16 + cb1/cb2) + kv_in/x2bf + input transpose ----------------
// blocks 0..287 weight convert, 288 cb1, 289 cb2, 290..1289 kvin, 1290+ transpose (lower -> xt)
__global__ __launch_bounds__(384) void k_pre_t(const float* __restrict__ qw, short* __restrict__ wq,
                        const float* __restrict__ kvw, short* __restrict__ wkv,
                        const float* __restrict__ c1w, short* __restrict__ wc1,
                        const float* __restrict__ c2w, short* __restrict__ wc2,
                        const float* __restrict__ c1b, const float* __restrict__ bn1b,
                        const float* __restrict__ c2b, const float* __restrict__ bn2b,
                        float* __restrict__ cb1, float* __restrict__ cb2,
                        const float* __restrict__ x, float* __restrict__ xt,
                        const float* __restrict__ lcw, const float* __restrict__ lcb,
                        short* __restrict__ x2bf, short* __restrict__ kvinbf) {
  __shared__ float tile[32][33];
  int bid = blockIdx.x;
  int tx = threadIdx.x, ty = threadIdx.y;
  int t = ty * 32 + tx;
  if (bid < 288) {
    if (t < 256) {
      const float* src; short* dst; int base;
      if (bid < 72)       { src = qw;  dst = wq;  base = bid; }
      else if (bid < 216) { src = kvw; dst = wkv; base = bid - 72; }
      else if (bid < 252) { src = c1w; dst = wc1; base = bid - 216; }
      else                { src = c2w; dst = wc2; base = bid - 252; }
      int i = (base * 256 + t) * 8;
      float4 a = *reinterpret_cast<const float4*>(&src[i]);
      float4 b = *reinterpret_cast<const float4*>(&src[i + 4]);
      short tmp[8] = {f2bf(a.x), f2bf(a.y), f2bf(a.z), f2bf(a.w),
                      f2bf(b.x), f2bf(b.y), f2bf(b.z), f2bf(b.w)};
      *(bf16x8*)&dst[i] = *(bf16x8*)tmp;
    }
  } else if (bid == 288) {
    if (t < 96) {
      float a = c1b[t];
      const float* wr = c1w + (size_t)t * C;
      for (int c = 0; c < C; c++) a += bn1b[c] * wr[c];
      cb1[t] = a;
    }
  } else if (bid == 289) {
    for (int o = t; o < C; o += 384) {
      float a = c2b[o];
      const float* wr = c2w + (size_t)o * 96;
      for (int i = 0; i < 96; i++) a += bn2b[i] * wr[i];
      cb2[o] = a;
    }
  } else if (bid < 1290) {
    int u = bid - 290;
    int b = u / 125, l0 = (u % 125) * 8, c = t;
    float w0 = lcw[c * 3], w1 = lcw[c * 3 + 1] + 1.0f, w2 = lcw[c * 3 + 2], bb = lcb[c];
    const float* xb = x + (size_t)b * L * C + C2 + c;
    float prev = (l0 > 0) ? xb[(size_t)(l0 - 1) * C] : 0.f;
    float cur  = (l0 < L) ? xb[(size_t)l0 * C] : 0.f;
    #pragma unroll
    for (int r = 0; r < 8; r++) {
      int l = l0 + r;
      if (l >= L) break;
      float nxt = (l + 1 < L) ? xb[(size_t)(l + 1) * C] : 0.f;
      x2bf[((size_t)b * L + l) * C2 + c]   = f2bf(cur);
      kvinbf[((size_t)b * L + l) * C2 + c] = f2bf(prev * w0 + cur * w1 + nxt * w2 + bb);
      prev = cur; cur = nxt;
    }
  } else {
    int tb = bid - 1290;
    int bx = tb % 32, by = (tb / 32) % 12, bz = tb / 384;
    int l0 = bx * 32, c0 = by * 32;
    if (ty < 8) {
      #pragma unroll
      for (int i = 0; i < 4; i++) {
        int l = l0 + ty + i * 8, c = c0 + tx;
        if (l < L) tile[ty + i * 8][tx] = x[((size_t)bz * L + l) * C + c];
      }
    }
    __syncthreads();
    if (ty < 8) {
      #pragma unroll
      for (int i = 0; i < 4; i++) {
        int c = c0 + ty + i * 8, l = l0 + tx;
        if (l < L) xt[((size_t)bz * C + c) * L + l] = tile[tx][ty + i * 8];
      }
    }
  }
}

// ---------------- pooled chunk means + row mean ----------------
__global__ __launch_bounds__(256) void k_pool(const float* __restrict__ xt,
                                              float* __restrict__ pooled,
                                              float* __restrict__ xm) {
  int c = blockIdx.x, b = blockIdx.y;
  const float* row = xt + ((size_t)b * C + c) * L;
  float s0 = 0.f, s1 = 0.f, s2 = 0.f;
  for (int l = threadIdx.x; l < L; l += 256) {
    float v = row[l];
    int ch = l / 333;
    if (ch == 0) s0 += v; else if (ch == 1) s1 += v; else s2 += v;
  }
  s0 = wave_sum(s0); s1 = wave_sum(s1); s2 = wave_sum(s2);
  __shared__ float r[3][4];
  int lane = threadIdx.x & 63, wid = threadIdx.x >> 6;
  if (lane == 0) { r[0][wid] = s0; r[1][wid] = s1; r[2][wid] = s2; }
  __syncthreads();
  if (threadIdx.x == 0) {
    float t0 = r[0][0] + r[0][1] + r[0][2] + r[0][3];
    float t1 = r[1][0] + r[1][1] + r[1][2] + r[1][3];
    float t2 = r[2][0] + r[2][1] + r[2][2] + r[2][3];
    size_t pb = (size_t)(b * C2 + c) * 3;
    pooled[pb + 0] = t0 / 333.f;
    pooled[pb + 1] = t1 / 333.f;
    pooled[pb + 2] = t2 / 333.f;
    xm[b * C2 + c] = (t0 + t1 + t2) / 999.f;
  }
}

// ---------------- tiny MLP layer 1 ----------------
__global__ void k_mlp1(const float* __restrict__ pooled, const float* __restrict__ xm,
                       const float* __restrict__ p1w, const float* __restrict__ p1b,
                       float* __restrict__ h1) {
  int j = blockIdx.x, b = blockIdx.y;
  __shared__ float vin[C2];
  for (int c = threadIdx.x; c < C2; c += 128)
    vin[c] = (j < 3) ? pooled[(size_t)(b * C2 + c) * 3 + j] : xm[b * C2 + c];
  __syncthreads();
  int o = threadIdx.x;
  if (o < 96) {
    float acc = p1b[o];
    const float* wr = p1w + (size_t)o * C2;
    for (int c = 0; c < C2; c++) acc += vin[c] * wr[c];
    h1[(b * 4 + j) * 96 + o] = gelu_f(acc);
  }
}

// ---------------- MLP layer 2 + softmax + mix ----------------
__global__ void k_mix2(const float* __restrict__ h1,
                       const float* __restrict__ p2w, const float* __restrict__ p2b,
                       const float* __restrict__ dcw, const float* __restrict__ dcb,
                       float* __restrict__ wdyn, float* __restrict__ bdyn) {
  int j = blockIdx.x, b = blockIdx.y;
  __shared__ float hv[96];
  for (int i = threadIdx.x; i < 96; i += 384) hv[i] = h1[(b * 4 + j) * 96 + i];
  __syncthreads();
  int c = threadIdx.x;
  float a0 = p2b[c], a1 = p2b[C2 + c];
  const float* w0r = p2w + (size_t)c * 96;
  const float* w1r = p2w + (size_t)(C2 + c) * 96;
  for (int i = 0; i < 96; i++) { float h = hv[i]; a0 += h * w0r[i]; a1 += h * w1r[i]; }
  float m = fmaxf(a0, a1);
  float e0 = __expf(a0 - m), e1 = __expf(a1 - m);
  float inv = 1.f / (e0 + e1);
  float p0 = e0 * inv, p1 = e1 * inv;
  if (j < 3)
    wdyn[(size_t)(b * C2 + c) * 3 + j] = p0 * dcw[(size_t)c * 3 + j] + p1 * dcw[(size_t)(C2 + c) * 3 + j];
  else
    bdyn[b * C2 + c] = p0 * dcb[c] + p1 * dcb[C2 + c];
}

// ---------------- dyn-conv (xt2 lower, fp32 [c][l]) ----------------
__global__ __launch_bounds__(256) void k_dwconv(const float* __restrict__ xt,
                                                const float* __restrict__ wdyn,
                                                const float* __restrict__ bdyn,
                                                float* __restrict__ xt2) {
  int c = blockIdx.x, b = blockIdx.y;
  const float* rowA = xt + ((size_t)b * C + c) * L;
  size_t wb = (size_t)(b * C2 + c) * 3;
  float a0 = wdyn[wb], a1 = wdyn[wb + 1], a2 = wdyn[wb + 2], ab = bdyn[b * C2 + c];
  float* oA = xt2 + ((size_t)b * C + c) * L;
  for (int l = threadIdx.x; l < L; l += 256) {
    float xm1 = (l > 0) ? rowA[l - 1] : 0.f;
    float x0 = rowA[l];
    float xp1 = (l < L - 1) ? rowA[l + 1] : 0.f;
    oA[l] = xm1 * a0 + x0 * a1 + xp1 * a2 + ab;
  }
}

// ---------------- GEMM device body (v3 structure, R4-measured) ----------------
template<int LT, bool XBF16>
__device__ __forceinline__ void gemm_body(const short* __restrict__ Wbf,
                                          const void* __restrict__ Xv,
                                          void* __restrict__ Yv,
                                          const float* __restrict__ ssum,
                                          const float* __restrict__ ssq,
                                          const float* __restrict__ sg,
                                          const float* __restrict__ bias,
                                          float* __restrict__ osum, float* __restrict__ osq,
                                          int O, int Kd, int Kstride, int XLd, int Ldy,
                                          size_t xbs, size_t ybs,
                                          int flags, float outmul,
                                          int kc, size_t slice,
                                          int o0, int l0, int b,
                                          short* Xt) {
  constexpr int R = LT / 32;
  constexpr int XSZ = LT * 72;
  int kbeg = kc * Kd;
  int t = threadIdx.x, w = t >> 6, lane = t & 63;
  int col = lane & 15, quad = lane >> 4;
  int KT = (Kd + 63) >> 6;

  floatx4 acc[LT / 16];
  #pragma unroll
  for (int i = 0; i < LT / 16; i++) acc[i] = floatx4{0.f, 0.f, 0.f, 0.f};

  int orow = o0 + w * 16 + col;
  bool wok = orow < O;
  const short* Wrow = Wbf + (size_t)orow * Kstride + kbeg;

  const short* Xb16 = (const short*)Xv + (size_t)b * xbs + kbeg;
  const float* Xb32 = (const float*)Xv + (size_t)b * xbs + kbeg;

  bf16x8 xr[R];
  float4 xf[R][2];
  bf16x8 wcur0, wcur1, wnxt0, wnxt1;

  auto xload = [&](int k0) {
    #pragma unroll
    for (int r = 0; r < R; r++) {
      int u = t + r * 256;
      int ll = u >> 3, oct = u & 7;
      int l = l0 + ll, kk = k0 + oct * 8;
      bool ok = (l < L) && (kk < Kd);
      if constexpr (XBF16) {
        xr[r] = ok ? *(const bf16x8*)&Xb16[(size_t)l * XLd + kk]
                   : bf16x8{0, 0, 0, 0, 0, 0, 0, 0};
      } else {
        if (ok) {
          const float* p = &Xb32[(size_t)l * XLd + kk];
          float4 a = *(const float4*)p;
          float4 bq = *(const float4*)(p + 4);
          if (sg) {
            float4 u0 = *(const float4*)&ssum[kbeg + kk];
            float4 u1 = *(const float4*)&ssum[kbeg + kk + 4];
            float4 q0 = *(const float4*)&ssq[kbeg + kk];
            float4 q1 = *(const float4*)&ssq[kbeg + kk + 4];
            float4 g0 = *(const float4*)&sg[kbeg + kk];
            float4 g1 = *(const float4*)&sg[kbeg + kk + 4];
            BNA(a.x, u0.x, q0.x, g0.x);  BNA(a.y, u0.y, q0.y, g0.y);
            BNA(a.z, u0.z, q0.z, g0.z);  BNA(a.w, u0.w, q0.w, g0.w);
            BNA(bq.x, u1.x, q1.x, g1.x); BNA(bq.y, u1.y, q1.y, g1.y);
            BNA(bq.z, u1.z, q1.z, g1.z); BNA(bq.w, u1.w, q1.w, g1.w);
          }
          xf[r][0] = a;
          xf[r][1] = bq;
        } else {
          xf[r][0] = float4{0.f, 0.f, 0.f, 0.f};
          xf[r][1] = float4{0.f, 0.f, 0.f, 0.f};
        }
      }
    }
  };
  auto xwrite = [&](int buf) {
    #pragma unroll
    for (int r = 0; r < R; r++) {
      int u = t + r * 256;
      int ll = u >> 3, oct = u & 7;
      bf16x8 val;
      if constexpr (XBF16) {
        val = xr[r];
      } else {
        union { unsigned u4[4]; bf16x8 v; } pk;
        asm("v_cvt_pk_bf16_f32 %0, %1, %2" : "=v"(pk.u4[0]) : "v"(xf[r][0].x), "v"(xf[r][0].y));
        asm("v_cvt_pk_bf16_f32 %0, %1, %2" : "=v"(pk.u4[1]) : "v"(xf[r][0].z), "v"(xf[r][0].w));
        asm("v_cvt_pk_bf16_f32 %0, %1, %2" : "=v"(pk.u4[2]) : "v"(xf[r][1].x), "v"(xf[r][1].y));
        asm("v_cvt_pk_bf16_f32 %0, %1, %2" : "=v"(pk.u4[3]) : "v"(xf[r][1].z), "v"(xf[r][1].w));
        val = pk.v;
      }
      *(bf16x8*)&Xt[buf * XSZ + ll * 72 + oct * 8] = val;
    }
  };
  auto wload = [&](int k0, bf16x8& f0, bf16x8& f1) {
    int kk0 = k0 + quad * 8;
    int kk1 = k0 + 32 + quad * 8;
    f0 = (wok && kk0 < Kd) ? *(const bf16x8*)&Wrow[kk0] : bf16x8{0, 0, 0, 0, 0, 0, 0, 0};
    f1 = (wok && kk1 < Kd) ? *(const bf16x8*)&Wrow[kk1] : bf16x8{0, 0, 0, 0, 0, 0, 0, 0};
  };

  // prologue
  xload(0);
  wload(0, wcur0, wcur1);
  xwrite(0);
  __syncthreads();

  for (int it = 0; it < KT; ++it) {
    int curb = it & 1;
    bool more = (it + 1 < KT);
    if (more) { xload((it + 1) * 64); wload((it + 1) * 64, wnxt0, wnxt1); }
    #pragma unroll
    for (int nt = 0; nt < LT / 16; nt++) {
      bf16x8 bx0 = *(bf16x8*)&Xt[curb * XSZ + (nt * 16 + col) * 72 + quad * 8];
      acc[nt] = __builtin_amdgcn_mfma_f32_16x16x32_bf16(wcur0, bx0, acc[nt], 0, 0, 0);
      bf16x8 bx1 = *(bf16x8*)&Xt[curb * XSZ + (nt * 16 + col) * 72 + 32 + quad * 8];
      acc[nt] = __builtin_amdgcn_mfma_f32_16x16x32_bf16(wcur1, bx1, acc[nt], 0, 0, 0);
    }
    if (more) xwrite(curb ^ 1);
    __syncthreads();
    wcur0 = wnxt0; wcur1 = wnxt1;
  }

  // ---- epilogue ----
  int o_base = o0 + w * 16 + quad * 4;
  #pragma unroll
  for (int r = 0; r < 4; r++) {
    int o = o_base + r;
    bool ov = o < O;
    float bo = (bias && ov) ? bias[o] : 0.f;
    float ps = 0.f, pq = 0.f;
    #pragma unroll
    for (int nt = 0; nt < LT / 16; nt++) {
      int l = l0 + nt * 16 + col;
      float v = acc[nt][r] + bo;
      if (flags & 1) v = gelu_f(v);
      v *= outmul;
      if (l >= L) v = 0.f;
      if (ov && l < L) {
        if (flags & 2) ((short*)Yv)[(size_t)b * ybs + (size_t)o * Ldy + l] = f2bf(v);
        else           ((float*)Yv)[kc * slice + (size_t)b * ybs + (size_t)o * Ldy + l] = v;
      }
      ps += v; pq += v * v;
    }
    if ((flags & 8) && ov) {
      ps += __shfl_xor(ps, 1); ps += __shfl_xor(ps, 2);
      ps += __shfl_xor(ps, 4); ps += __shfl_xor(ps, 8);
      pq += __shfl_xor(pq, 1); pq += __shfl_xor(pq, 2);
      pq += __shfl_xor(pq, 4); pq += __shfl_xor(pq, 8);
      if (col == 0) { atomicAdd(&osum[o], ps); atomicAdd(&osq[o], pq); }
    }
  }
}

// ---------------- generic GEMM wrapper (c1, c2) ----------------
template<int LT, bool XBF16>
__global__ __launch_bounds__(256) void k_gemm3(const short* __restrict__ Wbf,
                                               const void* __restrict__ Xv,
                                               void* __restrict__ Yv,
                                               const float* __restrict__ ssum,
                                               const float* __restrict__ ssq,
                                               const float* __restrict__ sg,
                                               const float* __restrict__ bias,
                                               float* __restrict__ osum, float* __restrict__ osq,
                                               int O, int Kd, int Kstride, int XLd, int Ldy,
                                               size_t xbs, size_t ybs,
                                               int flags, float outmul,
                                               int ksplit, size_t slice) {
  __shared__ __align__(16) short Xt[2][LT * 72];
  int kc = (int)blockIdx.y % ksplit;
  int o0 = ((int)blockIdx.y / ksplit) * 64;
  gemm_body<LT, XBF16>(Wbf, Xv, Yv, ssum, ssq, sg, bias, osum, osq,
                       O, Kd, Kstride, XLd, Ldy, xbs, ybs, flags, outmul,
                       kc, slice, o0, blockIdx.x * LT, blockIdx.z, &Xt[0][0]);
}

// ---------------- fused q + kv GEMM (one launch, block-uniform config) ----------------
// blockIdx.y 0..5: q (O=C2, out qbuf [o][L], *ATT_SCALE*LOG2E); 6..17: kv (O=C, out kvbuf [o][KVL])
__global__ __launch_bounds__(256) void k_gemm_qkv(const short* __restrict__ wq,
                                                  const short* __restrict__ wkv,
                                                  const short* __restrict__ x2,
                                                  const short* __restrict__ kvin,
                                                  short* __restrict__ qout,
                                                  short* __restrict__ kvout,
                                                  const float* __restrict__ qbias,
                                                  const float* __restrict__ kvbias) {
  __shared__ __align__(16) short Xt[2][128 * 72];
  int y = blockIdx.y;
  if (y < 6) {
    gemm_body<128, true>(wq, (const void*)x2, (void*)qout,
                         nullptr, nullptr, nullptr, qbias, nullptr, nullptr,
                         C2, C2, C2, C2, L, (size_t)C2 * L, (size_t)C2 * L,
                         2, ATT_SCALE * LOG2E, 0, 0,
                         y * 64, blockIdx.x * 128, blockIdx.z, &Xt[0][0]);
  } else {
    gemm_body<128, true>(wkv, (const void*)kvin, (void*)kvout,
                         nullptr, nullptr, nullptr, kvbias, nullptr, nullptr,
                         C, C2, C2, C2, KVL, (size_t)C2 * L, (size_t)C * KVL,
                         2, 1.0f, 0, 0,
                         (y - 6) * 64, blockIdx.x * 128, blockIdx.z, &Xt[0][0]);
  }
}

// ---------------- h2 finalize: sum 4 c1 partials + cb1, gelu, bn2 stats, write [l][96] ----------------
__global__ __launch_bounds__(256) void k_h2fin_t(const float* __restrict__ part,
                                                 const float* __restrict__ cb1,
                                                 float* __restrict__ h2,
                                                 float* __restrict__ sum, float* __restrict__ sq) {
  __shared__ float tile[96][33];
  __shared__ float lsum[96], lsq[96];
  constexpr size_t SL = (size_t)B * 96 * L;
  int b = blockIdx.y, l0 = blockIdx.x * 32;
  int t = threadIdx.x;
  #pragma unroll
  for (int p = 0; p < 12; p++) {
    int u = t + p * 256;
    int o = u >> 5, li = u & 31;
    int l = l0 + li;
    float v = 0.f;
    if (l < L) {
      size_t idx = ((size_t)b * 96 + o) * L + l;
      v = gelu_f(part[idx] + part[SL + idx] + part[2 * SL + idx] + part[3 * SL + idx] + cb1[o]);
    }
    tile[o][li] = v;
    float vs = v, vq = v * v;
    vs += __shfl_xor(vs, 1); vs += __shfl_xor(vs, 2); vs += __shfl_xor(vs, 4);
    vs += __shfl_xor(vs, 8); vs += __shfl_xor(vs, 16);
    vq += __shfl_xor(vq, 1); vq += __shfl_xor(vq, 2); vq += __shfl_xor(vq, 4);
    vq += __shfl_xor(vq, 8); vq += __shfl_xor(vq, 16);
    if ((t & 31) == 0) { lsum[o] = vs; lsq[o] = vq; }
  }
  __syncthreads();
  if (t < 96) { atomicAdd(&sum[t], lsum[t]); atomicAdd(&sq[t], lsq[t]); }
  #pragma unroll
  for (int p = 0; p < 12; p++) {
    int u = t + p * 256;
    int lr = u / 96, o = u % 96;
    int l = l0 + lr;
    if (l < L) h2[((size_t)b * L + l) * 96 + o] = tile[o][lr];
  }
}

// ---------------- MFMA flash attention: XCD-swizzled grid (bh fastest -> KV L2-resident) ----------------
__global__ __launch_bounds__(512, 4) void k_attn_mfma(const short* __restrict__ q,
                                                      const short* __restrict__ kv,
                                                      float* __restrict__ out) {
  __shared__ __align__(16) char smem[2 * 8192 + 2 * 6144 + 33280];  // 61952 B
  short* Ks0 = (short*)smem;
  short* Ks1 = (short*)(smem + 8192);
  short* Vf0 = (short*)(smem + 16384);
  short* Vf1 = (short*)(smem + 22528);
  float* PF  = (float*)(smem + 28672);
  float* Os  = (float*)smem;

  // grid (64, 8): bh fastest -> XCD = bh % 8 = h; each XCD holds one head's Q+KV (2.3 MB, L2-fits)
  int bh = blockIdx.x;
  int h = bh & 7, b = bh >> 3;
  int lt0 = blockIdx.y * 128;
  int t = threadIdx.x;
  int w = t >> 6, lane = t & 63;
  int col = lane & 15, quad = lane >> 4;
  const short* qb = q  + ((size_t)b * C2 + h * HD) * L;
  const short* kb = kv + ((size_t)b * C  + h * HD) * KVL;
  const short* vb = kv + ((size_t)b * C + C2 + h * HD) * KVL;

  bf16x8 aq0, aq1;
  {
    int l = lt0 + w * 16 + col;
    bool ok = l < L;
    const short* qp = qb + (size_t)(quad * 8) * L + l;
    short v0[8];
    #pragma unroll
    for (int jj = 0; jj < 8; jj++) v0[jj] = ok ? qp[(size_t)jj * L] : (short)0;
    aq0 = *(bf16x8*)v0;
    if (quad < 2) {
      const short* qp1 = qb + (size_t)(32 + quad * 8) * L + l;
      short v1[8];
      #pragma unroll
      for (int jj = 0; jj < 8; jj++) v1[jj] = ok ? qp1[(size_t)jj * L] : (short)0;
      aq1 = *(bf16x8*)v1;
    } else {
      aq1 = bf16x8{0, 0, 0, 0, 0, 0, 0, 0};
    }
  }

  short kreg[8];
  bf16x8 vreg;

  auto stage_load = [&](int m0) {
    if (t < 384) {
      int m = t & 63, j = t >> 6;
      int gm = m0 + m;
      bool ok = gm < L;
      const short* src = kb + (size_t)(8 * j) * KVL + gm;
      #pragma unroll
      for (int jj = 0; jj < 8; jj++) kreg[jj] = ok ? src[(size_t)jj * KVL] : (short)0;
    }
    if (t >= 128) {
      int a = t - 128;
      int d = (a & 7) | ((a >> 6) << 3);
      int o = (a >> 3) & 7;
      int mb = m0 + o * 8;
      const short* src = vb + (size_t)d * KVL + mb;
      if (mb + 8 <= L) {
        vreg = *(const bf16x8*)src;
      } else {
        short tmp[8];
        #pragma unroll
        for (int j = 0; j < 8; j++) tmp[j] = (mb + j < L) ? src[j] : (short)0;
        vreg = *(bf16x8*)tmp;
      }
    }
  };
  auto stage_write = [&](short* Kd, short* Vd) {
    if (t < 384) {
      int m = t & 63, j = t >> 6;
      int slot = ((m >> 4) * 2 + (j >> 2)) * 64 + (j & 3) * 16 + (m & 15);
      *(bf16x8*)&Kd[slot * 8] = *(bf16x8*)kreg;
    }
    if (t >= 128) {
      int a = t - 128;
      int d = (a & 7) | ((a >> 6) << 3);
      int o = (a >> 3) & 7;
      int lanep = ((o & 3) << 4) | (d & 15);
      *(bf16x8*)&Vd[(((o >> 2) * 3 + (d >> 4)) * 64 + lanep) * 8] = vreg;
    }
  };

  if (t < 256) {
    int i = t & 127;
    int ms = i >> 5, qq = 2 + ((i >> 4) & 1), cc = i & 15;
    int slot = (ms * 2 + 1) * 64 + qq * 16 + cc;
    short* Kd = (t < 128) ? Ks0 : Ks1;
    *(bf16x8*)&Kd[slot * 8] = bf16x8{0, 0, 0, 0, 0, 0, 0, 0};
  }

  stage_load(0);
  stage_write(Ks0, Vf0);

  floatx4 of[3];
  #pragma unroll
  for (int i = 0; i < 3; i++) of[i] = floatx4{0.f, 0.f, 0.f, 0.f};
  float rs[4] = {0.f, 0.f, 0.f, 0.f};
  __syncthreads();

  for (int it = 0; it < 16; ++it) {
    int m0 = it * 64;
    short* Kc = (it & 1) ? Ks1 : Ks0;
    short* Vc = (it & 1) ? Vf1 : Vf0;
    short* Kn = (it & 1) ? Ks0 : Ks1;
    short* Vn = (it & 1) ? Vf0 : Vf1;
    if (it < 15) stage_load(m0 + 64);

    floatx4 sf[4];
    __builtin_amdgcn_s_setprio(1);
    #pragma unroll
    for (int ms = 0; ms < 4; ms++) {
      bf16x8 bk0 = *(bf16x8*)&Kc[((ms * 2 + 0) * 64 + lane) * 8];
      bf16x8 bk1 = *(bf16x8*)&Kc[((ms * 2 + 1) * 64 + lane) * 8];
      floatx4 a4 = floatx4{0.f, 0.f, 0.f, 0.f};
      a4 = __builtin_amdgcn_mfma_f32_16x16x32_bf16(aq0, bk0, a4, 0, 0, 0);
      a4 = __builtin_amdgcn_mfma_f32_16x16x32_bf16(aq1, bk1, a4, 0, 0, 0);
      sf[ms] = a4;
    }
    __builtin_amdgcn_s_setprio(0);

    float* pw = PF + w * 1040 + lane;
    #pragma unroll
    for (int ms = 0; ms < 4; ms++) {
      int m = m0 + ms * 16 + col;
      bool ok = m < L;
      #pragma unroll
      for (int r = 0; r < 4; r++) {
        float e = ok ? exp2_hw(sf[ms][r]) : 0.f;
        rs[r] += e;
        pw[(ms * 4 + r) * 65] = e;
      }
    }

    const float* pr = PF + w * 1040 + (col & 3) * 65 + (col >> 2) * 16 + (quad & 1) * 8;
    __builtin_amdgcn_s_setprio(1);
    #pragma unroll
    for (int mh = 0; mh < 2; mh++) {
      const float* ps = pr + (mh * 2 + (quad >> 1)) * 260;
      float p8[8];
      #pragma unroll
      for (int jj = 0; jj < 8; jj++) p8[jj] = ps[jj];
      bf16x8 ap = pack8(p8);
      #pragma unroll
      for (int ds = 0; ds < 3; ds++) {
        bf16x8 bv = *(bf16x8*)&Vc[((mh * 3 + ds) * 64 + lane) * 8];
        of[ds] = __builtin_amdgcn_mfma_f32_16x16x32_bf16(ap, bv, of[ds], 0, 0, 0);
      }
    }
    __builtin_amdgcn_s_setprio(0);
    if (it < 15) stage_write(Kn, Vn);
    __syncthreads();
  }

  #pragma unroll
  for (int r = 0; r < 4; r++) {
    float v = rs[r];
    v += __shfl_xor(v, 1); v += __shfl_xor(v, 2);
    v += __shfl_xor(v, 4); v += __shfl_xor(v, 8);
    rs[r] = v;
  }
  #pragma unroll
  for (int r = 0; r < 4; r++) {
    float inv = 1.f / rs[r];
    #pragma unroll
    for (int ds = 0; ds < 3; ds++)
      Os[(ds * 16 + col) * 130 + w * 16 + quad * 4 + r] = of[ds][r] * inv;
  }
  __syncthreads();
  for (int i = t; i < 48 * 128; i += 512) {
    int d = i >> 7, ll = i & 127;
    int l = lt0 + ll;
    if (l < L) out[((size_t)b * C2 + h * HD + d) * L + l] = Os[d * 130 + ll];
  }
}

// ---------------- projection dw3 + gelu -> t1 [l][C], bn1 stats ----------------
__global__ __launch_bounds__(256) void k_dwproj_t(const float* __restrict__ xt2,
                                                  const float* __restrict__ ao,
                                                  const float* __restrict__ dww,
                                                  const float* __restrict__ dwb,
                                                  float* __restrict__ t1,
                                                  float* __restrict__ sum, float* __restrict__ sq) {
  __shared__ float tile[32][67];
  __shared__ float rs[4][32], rq[4][32];
  int b = blockIdx.z, c0 = blockIdx.y * 32, l0 = blockIdx.x * 64;
  int t = threadIdx.x;
  if (c0 < C2) {
    for (int u = t; u < 32 * 66; u += 256) {
      int cc = u / 66, li = u % 66;
      int l = l0 - 1 + li;
      tile[cc][li] = (l >= 0 && l < L) ? xt2[((size_t)b * C + c0 + cc) * L + l] : 0.f;
    }
  } else {
    for (int u = t; u < 32 * 66; u += 256) {
      int li = u >> 5, cc = u & 31;
      int l = l0 - 1 + li;
      tile[cc][li] = (l >= 0 && l < L) ? ao[((size_t)b * L + l) * C2 + (c0 - C2 + cc)] : 0.f;
    }
  }
  __syncthreads();
  int c = c0 + (t & 31);
  float w0 = dww[c * 3], w1 = dww[c * 3 + 1], w2 = dww[c * 3 + 2], bb = dwb[c];
  int cc = t & 31;
  float s = 0.f, s2 = 0.f;
  #pragma unroll
  for (int p = 0; p < 8; p++) {
    int lr = (t >> 5) + p * 8;
    int l = l0 + lr;
    float v = 0.f;
    if (l < L) {
      v = gelu_f(tile[cc][lr] * w0 + tile[cc][lr + 1] * w1 + tile[cc][lr + 2] * w2 + bb);
      t1[((size_t)b * L + l) * C + c] = v;
    }
    s += v; s2 += v * v;
  }
  s += __shfl_xor(s, 32, 64); s2 += __shfl_xor(s2, 32, 64);
  int wv = t >> 6, ln = t & 63;
  if (ln < 32) { rs[wv][ln] = s; rq[wv][ln] = s2; }
  __syncthreads();
  if (t < 32) {
    float a = rs[0][t] + rs[1][t] + rs[2][t] + rs[3][t];
    float qq = rq[0][t] + rq[1][t] + rq[2][t] + rq[3][t];
    atomicAdd(&sum[c0 + t], a);
    atomicAdd(&sq[c0 + t], qq);
  }
}

// ---------------- final: out[b,l,c] = bn3(y3) + residual, bn3 inlined from sums ----------------
__global__ void k_final(const float* __restrict__ y3, const float* __restrict__ xt2,
                        const float* __restrict__ ao,
                        const float* __restrict__ sum3, const float* __restrict__ sq3,
                        const float* __restrict__ bn3g, const float* __restrict__ bn3b,
                        float* __restrict__ out) {
  __shared__ float tile[32][33];
  int b = blockIdx.z;
  int l0 = blockIdx.x * 32, c0 = blockIdx.y * 32;
  int tx = threadIdx.x, ty = threadIdx.y;
  #pragma unroll
  for (int i = 0; i < 4; i++) {
    int c = c0 + ty + i * 8, l = l0 + tx;
    if (l < L) {
      float m = sum3[c] * INV_N;
      float v = sq3[c] * INV_N - m * m;
      float sc = bn3g[c] * rsqrtf(v + BN_EPS);
      float dd = bn3b[c] - m * sc;
      size_t idx = ((size_t)b * C + c) * L + l;
      float val = y3[idx] * sc + dd;
      if (c < C2) val += xt2[idx];
      tile[ty + i * 8][tx] = val;
    }
  }
  __syncthreads();
  #pragma unroll
  for (int i = 0; i < 4; i++) {
    int l = l0 + ty + i * 8, c = c0 + tx;
    if (l < L) {
      float val = tile[tx][ty + i * 8];
      if (c >= C2) val += ao[((size_t)b * L + l) * C2 + (c - C2)];
      out[((size_t)b * L + l) * C + c] = val;
    }
  }
}

extern "C" void kernel_launch(void* const* d_in, const int* in_sizes, int n_in,
                              void* d_out, int out_size, void* d_ws, size_t ws_size,
                              hipStream_t stream) {
  const float* x    = (const float*)d_in[0];
  const float* dcw  = (const float*)d_in[1];
  const float* dcb  = (const float*)d_in[2];
  const float* p1w  = (const float*)d_in[3];
  const float* p1b  = (const float*)d_in[4];
  const float* p2w  = (const float*)d_in[5];
  const float* p2b  = (const float*)d_in[6];
  const float* qw   = (const float*)d_in[7];
  const float* qb   = (const float*)d_in[8];
  const float* kvw  = (const float*)d_in[9];
  const float* kvb  = (const float*)d_in[10];
  const float* lcw  = (const float*)d_in[11];
  const float* lcb  = (const float*)d_in[12];
  const float* dww  = (const float*)d_in[13];
  const float* dwb  = (const float*)d_in[14];
  const float* bn1g = (const float*)d_in[15];
  const float* bn1b = (const float*)d_in[16];
  const float* c1w  = (const float*)d_in[17];
  const float* c1b  = (const float*)d_in[18];
  const float* bn2g = (const float*)d_in[19];
  const float* bn2b = (const float*)d_in[20];
  const float* c2w  = (const float*)d_in[21];
  const float* c2b  = (const float*)d_in[22];
  const float* bn3g = (const float*)d_in[23];
  const float* bn3b = (const float*)d_in[24];
  float* out = (float*)d_out;
  float* ws  = (float*)d_ws;

  float* xt      = ws + OFF_XT;                      // fp32 [c][l], later t1 [l][C]
  float* xt2     = ws + OFF_XT2;                     // fp32 [c][l] lower half only
  short* kvbuf   = (short*)(ws + OFF_KV);            // bf16 kv [o][KVL]
  float* c1part  = ws + OFF_KV;                      // fp32 4 slices (kvbuf dead after attn)
  float* y3      = ws + OFF_KV;                      // fp32 (c1part dead after h2fin)
  short* x2bf    = (short*)(ws + OFF_AX);            // bf16 x2 [l][c]
  short* kvinbf  = (short*)(ws + OFF_AX + SZ_HALF / 2);  // bf16 kv_in [l][c]
  float* attnout = ws + OFF_AX;                      // fp32, live until k_final
  short* qbuf    = (short*)(ws + OFF_Q);             // bf16 q [o][l]
  float* h2      = ws + OFF_Q;                       // fp32 [l][96] (reuse)
  float* sm      = ws + OFF_SM;

  float* pooled = sm + SM_POOLED;
  float* xm     = sm + SM_XM;
  float* h1     = sm + SM_H1;
  float* wdyn   = sm + SM_WDYN;
  float* bdyn   = sm + SM_BDYN;
  float* sum1 = sm + SM_SUM1; float* sq1 = sm + SM_SQ1;
  float* cb1 = sm + SM_CB1;
  float* sum2 = sm + SM_SUM2; float* sq2 = sm + SM_SQ2;
  float* cb2 = sm + SM_CB2;
  float* sum3 = sm + SM_SUM3; float* sq3 = sm + SM_SQ3;
  short* wqbf  = (short*)(sm + SM_WQ);
  short* wkvbf = (short*)(sm + SM_WKV);
  short* wc1bf = (short*)(sm + SM_WC1);
  short* wc2bf = (short*)(sm + SM_WC2);

  hipMemsetAsync((void*)(sm + SM_SUM1), 0, (SM_ZEND - SM_SUM1) * sizeof(float), stream);

  dim3 tb38(32, 12);
  dim3 tb32(32, 8);
  // 0. fused prep (weights + cb1/cb2) + kvin/x2bf + input transpose
  k_pre_t<<<4362, tb38, 0, stream>>>(qw, wqbf, kvw, wkvbf, c1w, wc1bf, c2w, wc2bf,
                                     c1b, bn1b, c2b, bn2b, cb1, cb2, x, xt,
                                     lcw, lcb, x2bf, kvinbf);
  // 1. pooled / mean
  k_pool<<<dim3(C2, B), 256, 0, stream>>>(xt, pooled, xm);
  // 2. tiny MLP
  k_mlp1<<<dim3(4, B), 128, 0, stream>>>(pooled, xm, p1w, p1b, h1);
  k_mix2<<<dim3(4, B), 384, 0, stream>>>(h1, p2w, p2b, dcw, dcb, wdyn, bdyn);
  // 3. dyn-conv -> xt2 lower
  k_dwconv<<<dim3(C2, B), 256, 0, stream>>>(xt, wdyn, bdyn, xt2);
  // 4. fused q + kv GEMM (one launch, 1152 blocks)
  k_gemm_qkv<<<dim3(8, 18, B), 256, 0, stream>>>(wqbf, wkvbf, x2bf, kvinbf,
                                                 qbuf, kvbuf, qb, kvb);
  // 5. MFMA flash attention -> attnout (XCD-swizzled grid: bh fastest)
  k_attn_mfma<<<dim3(64, 8), 512, 0, stream>>>(qbuf, kvbuf, attnout);
  // 6. projection dw3+gelu -> t1 [l][C] (reads xt2 lower + ao upper), bn1 stats
  k_dwproj_t<<<dim3(16, 24, B), 256, 0, stream>>>(xt2, attnout, dww, dwb, xt, sum1, sq1);
  // 7. c1 GEMM, K-split x4, BN1 inlined from sums -> c1part (in dead kvbuf region)
  k_gemm3<128, false><<<dim3(8, 8, B), 256, 0, stream>>>(
      wc1bf, (const void*)xt, (void*)c1part, sum1, sq1, bn1g, nullptr, nullptr, nullptr,
      96, 192, C, C, L, (size_t)C * L, (size_t)96 * L, 0, 1.0f, 4, (size_t)B * 96 * L);
  // 7b. h2 = gelu(sum partials + cb1) -> [l][96], bn2 stats
  k_h2fin_t<<<dim3(32, B), 256, 0, stream>>>(c1part, cb1, h2, sum2, sq2);
  // 8. c2 GEMM, BN2 inlined from sums, fp32 out y3, bn3 stats
  k_gemm3<128, false><<<dim3(8, 12, B), 256, 0, stream>>>(
      wc2bf, (const void*)h2, (void*)y3, sum2, sq2, bn2g, cb2, sum3, sq3,
      C, 96, 96, 96, L, (size_t)96 * L, (size_t)C * L, 8, 1.0f, 1, 0);
  // 9. final: bn3 (inlined) + residual (xt2 lower / ao upper) + transpose back
  k_final<<<dim3(32, 24, B), tb32, 0, stream>>>(y3, xt2, attnout, sum3, sq3, bn3g, bn3b, out);
}

// Round 9
// 321.154 us; speedup vs baseline: 1.0474x; 1.0474x over previous
//
#include <hip/hip_runtime.h>
#include <cstddef>

constexpr int B = 8, L = 999, C = 768, C2 = 384, H = 8, HD = 48;
constexpr int KVL = 1000;                            // kv buffer row stride (16B-aligned rows)
constexpr float ATT_SCALE = 0.14433756729740644f;   // 48^-0.5
constexpr float LOG2E = 1.4426950408889634f;
constexpr float BN_EPS = 1e-5f;
constexpr float INV_N = 1.0f / (8.0f * 999.0f);     // 1/(B*L)

constexpr size_t SZ_XT   = (size_t)B * C * L;       // 6,137,856
constexpr size_t SZ_HALF = (size_t)B * C2 * L;      // 3,068,928 = 4 * (B*96*L)
constexpr size_t OFF_XT  = 0;                       // xt fp32 [c][l], later t1 [l][C]
constexpr size_t OFF_XT2 = SZ_XT;                   // xt2 fp32 [c][l] (lower half only)
constexpr size_t OFF_KV  = 2 * SZ_XT;               // kv bf16 [o][KVL] -> c1part fp32 -> y3 fp32
constexpr size_t OFF_AX  = 3 * SZ_XT;               // x2bf+kvinbf (bf16 [l][c]) -> attnout fp32 (live to end)
constexpr size_t OFF_Q   = 3 * SZ_XT + SZ_HALF;     // q bf16 [o][l], later h2 fp32 [l][96]
constexpr size_t OFF_SM  = 3 * SZ_XT + SZ_HALF + SZ_HALF / 2;

// small-region offsets (floats, relative to OFF_SM)
constexpr size_t SM_POOLED = 0;       // B*C2*3
constexpr size_t SM_XM     = 9216;    // B*C2
constexpr size_t SM_WDYN   = 15360;   // B*C2*3
constexpr size_t SM_BDYN   = 24576;   // B*C2
constexpr size_t SM_SUM1   = 27648;   // 768
constexpr size_t SM_SQ1    = 28416;
constexpr size_t SM_CB1    = 30720;   // 96
constexpr size_t SM_SUM2   = 30816;   // 96
constexpr size_t SM_SQ2    = 30912;
constexpr size_t SM_CB2    = 31200;   // 768
constexpr size_t SM_SUM3   = 31968;
constexpr size_t SM_SQ3    = 32736;
constexpr size_t SM_ZEND   = 33504;   // memset end
constexpr size_t SM_END    = 35040;
// bf16 weight copies (float-slot offsets relative to OFF_SM)
constexpr size_t SM_WQ  = SM_END;
constexpr size_t SM_WKV = SM_WQ + 73728;
constexpr size_t SM_WC1 = SM_WKV + 147456;
constexpr size_t SM_WC2 = SM_WC1 + 36864;

typedef __attribute__((ext_vector_type(8))) short bf16x8;
typedef __attribute__((ext_vector_type(4))) float floatx4;

__device__ __forceinline__ float gelu_f(float x) {
  return 0.5f * x * (1.0f + erff(x * 0.70710678118654752f));
}

__device__ __forceinline__ float wave_sum(float v) {
  #pragma unroll
  for (int off = 32; off > 0; off >>= 1) v += __shfl_down(v, off, 64);
  return v;
}

__device__ __forceinline__ short f2bf(float f) {
  union { float f; unsigned u; } x; x.f = f;
  unsigned r = x.u + 0x7FFFu + ((x.u >> 16) & 1u);
  return (short)(r >> 16);
}

__device__ __forceinline__ float exp2_hw(float x) {
  float r;
  asm("v_exp_f32 %0, %1" : "=v"(r) : "v"(x));
  return r;
}

// BN inline: same fp32 expression as old k_bnfin -> bitwise identical
#define BNA(x, su, qq, gg) { float m_ = (su) * INV_N; float v_ = (qq) * INV_N - m_ * m_; \
  float sc_ = (gg) * rsqrtf(v_ + BN_EPS); (x) = ((x) - m_) * sc_; }

// ---------------- fused prep (weights bf16 + cb1/cb2) + input transpose (R7-measured) ----------------
// blocks 0..287 weight convert, 288 cb1, 289 cb2, 290+ transpose x lower -> xt [c][l]
__global__ void k_pre_t(const float* __restrict__ qw, short* __restrict__ wq,
                        const float* __restrict__ kvw, short* __restrict__ wkv,
                        const float* __restrict__ c1w, short* __restrict__ wc1,
                        const float* __restrict__ c2w, short* __restrict__ wc2,
                        const float* __restrict__ c1b, const float* __restrict__ bn1b,
                        const float* __restrict__ c2b, const float* __restrict__ bn2b,
                        float* __restrict__ cb1, float* __restrict__ cb2,
                        const float* __restrict__ x, float* __restrict__ xt) {
  __shared__ float tile[32][33];
  int bid = blockIdx.x;
  int t = threadIdx.y * 32 + threadIdx.x;
  if (bid < 288) {
    const float* src; short* dst; int base;
    if (bid < 72)       { src = qw;  dst = wq;  base = bid; }
    else if (bid < 216) { src = kvw; dst = wkv; base = bid - 72; }
    else if (bid < 252) { src = c1w; dst = wc1; base = bid - 216; }
    else                { src = c2w; dst = wc2; base = bid - 252; }
    int i = (base * 256 + t) * 8;
    float4 a = *reinterpret_cast<const float4*>(&src[i]);
    float4 b = *reinterpret_cast<const float4*>(&src[i + 4]);
    short tmp[8] = {f2bf(a.x), f2bf(a.y), f2bf(a.z), f2bf(a.w),
                    f2bf(b.x), f2bf(b.y), f2bf(b.z), f2bf(b.w)};
    *(bf16x8*)&dst[i] = *(bf16x8*)tmp;
  } else if (bid == 288) {
    if (t < 96) {
      float a = c1b[t];
      const float* wr = c1w + (size_t)t * C;
      for (int c = 0; c < C; c++) a += bn1b[c] * wr[c];
      cb1[t] = a;
    }
  } else if (bid == 289) {
    for (int o = t; o < C; o += 256) {
      float a = c2b[o];
      const float* wr = c2w + (size_t)o * 96;
      for (int i = 0; i < 96; i++) a += bn2b[i] * wr[i];
      cb2[o] = a;
    }
  } else {
    int tb = bid - 290;
    int bx = tb % 32, by = (tb / 32) % 12, bz = tb / 384;
    int l0 = bx * 32, c0 = by * 32;
    int tx = threadIdx.x, ty = threadIdx.y;
    #pragma unroll
    for (int i = 0; i < 4; i++) {
      int l = l0 + ty + i * 8, c = c0 + tx;
      if (l < L) tile[ty + i * 8][tx] = x[((size_t)bz * L + l) * C + c];
    }
    __syncthreads();
    #pragma unroll
    for (int i = 0; i < 4; i++) {
      int c = c0 + ty + i * 8, l = l0 + tx;
      if (l < L) xt[((size_t)bz * C + c) * L + l] = tile[tx][ty + i * 8];
    }
  }
}

// ---------------- kv_in + x2bf directly from x, [l][c] layout ----------------
__global__ __launch_bounds__(384) void k_kvin(const float* __restrict__ x,
                                              const float* __restrict__ lcw,
                                              const float* __restrict__ lcb,
                                              short* __restrict__ x2bf,
                                              short* __restrict__ kvinbf) {
  int b = blockIdx.y, l0 = blockIdx.x * 8, c = threadIdx.x;
  float w0 = lcw[c * 3], w1 = lcw[c * 3 + 1] + 1.0f, w2 = lcw[c * 3 + 2], bb = lcb[c];
  const float* xb = x + (size_t)b * L * C + C2 + c;
  float prev = (l0 > 0) ? xb[(size_t)(l0 - 1) * C] : 0.f;
  float cur  = (l0 < L) ? xb[(size_t)l0 * C] : 0.f;
  #pragma unroll
  for (int r = 0; r < 8; r++) {
    int l = l0 + r;
    if (l >= L) break;
    float nxt = (l + 1 < L) ? xb[(size_t)(l + 1) * C] : 0.f;
    x2bf[((size_t)b * L + l) * C2 + c]   = f2bf(cur);
    kvinbf[((size_t)b * L + l) * C2 + c] = f2bf(prev * w0 + cur * w1 + nxt * w2 + bb);
    prev = cur; cur = nxt;
  }
}

// ---------------- pooled chunk means + row mean ----------------
__global__ __launch_bounds__(256) void k_pool(const float* __restrict__ xt,
                                              float* __restrict__ pooled,
                                              float* __restrict__ xm) {
  int c = blockIdx.x, b = blockIdx.y;
  const float* row = xt + ((size_t)b * C + c) * L;
  float s0 = 0.f, s1 = 0.f, s2 = 0.f;
  for (int l = threadIdx.x; l < L; l += 256) {
    float v = row[l];
    int ch = l / 333;
    if (ch == 0) s0 += v; else if (ch == 1) s1 += v; else s2 += v;
  }
  s0 = wave_sum(s0); s1 = wave_sum(s1); s2 = wave_sum(s2);
  __shared__ float r[3][4];
  int lane = threadIdx.x & 63, wid = threadIdx.x >> 6;
  if (lane == 0) { r[0][wid] = s0; r[1][wid] = s1; r[2][wid] = s2; }
  __syncthreads();
  if (threadIdx.x == 0) {
    float t0 = r[0][0] + r[0][1] + r[0][2] + r[0][3];
    float t1 = r[1][0] + r[1][1] + r[1][2] + r[1][3];
    float t2 = r[2][0] + r[2][1] + r[2][2] + r[2][3];
    size_t pb = (size_t)(b * C2 + c) * 3;
    pooled[pb + 0] = t0 / 333.f;
    pooled[pb + 1] = t1 / 333.f;
    pooled[pb + 2] = t2 / 333.f;
    xm[b * C2 + c] = (t0 + t1 + t2) / 999.f;
  }
}

// ---------------- fused tiny MLP (mlp1 -> gelu -> mlp2 -> softmax -> mix), h1 in LDS ----------------
__global__ __launch_bounds__(384) void k_mlp_mix(const float* __restrict__ pooled,
                                                 const float* __restrict__ xm,
                                                 const float* __restrict__ p1w,
                                                 const float* __restrict__ p1b,
                                                 const float* __restrict__ p2w,
                                                 const float* __restrict__ p2b,
                                                 const float* __restrict__ dcw,
                                                 const float* __restrict__ dcb,
                                                 float* __restrict__ wdyn,
                                                 float* __restrict__ bdyn) {
  int j = blockIdx.x, b = blockIdx.y;
  __shared__ float vin[C2];
  __shared__ float hv[96];
  int t = threadIdx.x;
  for (int c = t; c < C2; c += 384)
    vin[c] = (j < 3) ? pooled[(size_t)(b * C2 + c) * 3 + j] : xm[b * C2 + c];
  __syncthreads();
  if (t < 96) {
    float acc = p1b[t];
    const float* wr = p1w + (size_t)t * C2;
    for (int c = 0; c < C2; c++) acc += vin[c] * wr[c];
    hv[t] = gelu_f(acc);
  }
  __syncthreads();
  int c = t;
  float a0 = p2b[c], a1 = p2b[C2 + c];
  const float* w0r = p2w + (size_t)c * 96;
  const float* w1r = p2w + (size_t)(C2 + c) * 96;
  for (int i = 0; i < 96; i++) { float h = hv[i]; a0 += h * w0r[i]; a1 += h * w1r[i]; }
  float m = fmaxf(a0, a1);
  float e0 = __expf(a0 - m), e1 = __expf(a1 - m);
  float inv = 1.f / (e0 + e1);
  float p0 = e0 * inv, p1 = e1 * inv;
  if (j < 3)
    wdyn[(size_t)(b * C2 + c) * 3 + j] = p0 * dcw[(size_t)c * 3 + j] + p1 * dcw[(size_t)(C2 + c) * 3 + j];
  else
    bdyn[b * C2 + c] = p0 * dcb[c] + p1 * dcb[C2 + c];
}

// ---------------- dyn-conv (xt2 lower, fp32 [c][l]) ----------------
__global__ __launch_bounds__(256) void k_dwconv(const float* __restrict__ xt,
                                                const float* __restrict__ wdyn,
                                                const float* __restrict__ bdyn,
                                                float* __restrict__ xt2) {
  int c = blockIdx.x, b = blockIdx.y;
  const float* rowA = xt + ((size_t)b * C + c) * L;
  size_t wb = (size_t)(b * C2 + c) * 3;
  float a0 = wdyn[wb], a1 = wdyn[wb + 1], a2 = wdyn[wb + 2], ab = bdyn[b * C2 + c];
  float* oA = xt2 + ((size_t)b * C + c) * L;
  for (int l = threadIdx.x; l < L; l += 256) {
    float xm1 = (l > 0) ? rowA[l - 1] : 0.f;
    float x0 = rowA[l];
    float xp1 = (l < L - 1) ? rowA[l + 1] : 0.f;
    oA[l] = xm1 * a0 + x0 * a1 + xp1 * a2 + ab;
  }
}

// ---------------- GEMM device body (v3 structure, R4-measured) ----------------
template<int LT, bool XBF16>
__device__ __forceinline__ void gemm_body(const short* __restrict__ Wbf,
                                          const void* __restrict__ Xv,
                                          void* __restrict__ Yv,
                                          const float* __restrict__ ssum,
                                          const float* __restrict__ ssq,
                                          const float* __restrict__ sg,
                                          const float* __restrict__ bias,
                                          float* __restrict__ osum, float* __restrict__ osq,
                                          int O, int Kd, int Kstride, int XLd, int Ldy,
                                          size_t xbs, size_t ybs,
                                          int flags, float outmul,
                                          int kc, size_t slice,
                                          int o0, int l0, int b,
                                          short* Xt) {
  constexpr int R = LT / 32;
  constexpr int XSZ = LT * 72;
  int kbeg = kc * Kd;
  int t = threadIdx.x, w = t >> 6, lane = t & 63;
  int col = lane & 15, quad = lane >> 4;
  int KT = (Kd + 63) >> 6;

  floatx4 acc[LT / 16];
  #pragma unroll
  for (int i = 0; i < LT / 16; i++) acc[i] = floatx4{0.f, 0.f, 0.f, 0.f};

  int orow = o0 + w * 16 + col;
  bool wok = orow < O;
  const short* Wrow = Wbf + (size_t)orow * Kstride + kbeg;

  const short* Xb16 = (const short*)Xv + (size_t)b * xbs + kbeg;
  const float* Xb32 = (const float*)Xv + (size_t)b * xbs + kbeg;

  bf16x8 xr[R];
  float4 xf[R][2];
  bf16x8 wcur0, wcur1, wnxt0, wnxt1;

  auto xload = [&](int k0) {
    #pragma unroll
    for (int r = 0; r < R; r++) {
      int u = t + r * 256;
      int ll = u >> 3, oct = u & 7;
      int l = l0 + ll, kk = k0 + oct * 8;
      bool ok = (l < L) && (kk < Kd);
      if constexpr (XBF16) {
        xr[r] = ok ? *(const bf16x8*)&Xb16[(size_t)l * XLd + kk]
                   : bf16x8{0, 0, 0, 0, 0, 0, 0, 0};
      } else {
        if (ok) {
          const float* p = &Xb32[(size_t)l * XLd + kk];
          float4 a = *(const float4*)p;
          float4 bq = *(const float4*)(p + 4);
          if (sg) {
            float4 u0 = *(const float4*)&ssum[kbeg + kk];
            float4 u1 = *(const float4*)&ssum[kbeg + kk + 4];
            float4 q0 = *(const float4*)&ssq[kbeg + kk];
            float4 q1 = *(const float4*)&ssq[kbeg + kk + 4];
            float4 g0 = *(const float4*)&sg[kbeg + kk];
            float4 g1 = *(const float4*)&sg[kbeg + kk + 4];
            BNA(a.x, u0.x, q0.x, g0.x);  BNA(a.y, u0.y, q0.y, g0.y);
            BNA(a.z, u0.z, q0.z, g0.z);  BNA(a.w, u0.w, q0.w, g0.w);
            BNA(bq.x, u1.x, q1.x, g1.x); BNA(bq.y, u1.y, q1.y, g1.y);
            BNA(bq.z, u1.z, q1.z, g1.z); BNA(bq.w, u1.w, q1.w, g1.w);
          }
          xf[r][0] = a;
          xf[r][1] = bq;
        } else {
          xf[r][0] = float4{0.f, 0.f, 0.f, 0.f};
          xf[r][1] = float4{0.f, 0.f, 0.f, 0.f};
        }
      }
    }
  };
  auto xwrite = [&](int buf) {
    #pragma unroll
    for (int r = 0; r < R; r++) {
      int u = t + r * 256;
      int ll = u >> 3, oct = u & 7;
      bf16x8 val;
      if constexpr (XBF16) {
        val = xr[r];
      } else {
        union { unsigned u4[4]; bf16x8 v; } pk;
        asm("v_cvt_pk_bf16_f32 %0, %1, %2" : "=v"(pk.u4[0]) : "v"(xf[r][0].x), "v"(xf[r][0].y));
        asm("v_cvt_pk_bf16_f32 %0, %1, %2" : "=v"(pk.u4[1]) : "v"(xf[r][0].z), "v"(xf[r][0].w));
        asm("v_cvt_pk_bf16_f32 %0, %1, %2" : "=v"(pk.u4[2]) : "v"(xf[r][1].x), "v"(xf[r][1].y));
        asm("v_cvt_pk_bf16_f32 %0, %1, %2" : "=v"(pk.u4[3]) : "v"(xf[r][1].z), "v"(xf[r][1].w));
        val = pk.v;
      }
      *(bf16x8*)&Xt[buf * XSZ + ll * 72 + oct * 8] = val;
    }
  };
  auto wload = [&](int k0, bf16x8& f0, bf16x8& f1) {
    int kk0 = k0 + quad * 8;
    int kk1 = k0 + 32 + quad * 8;
    f0 = (wok && kk0 < Kd) ? *(const bf16x8*)&Wrow[kk0] : bf16x8{0, 0, 0, 0, 0, 0, 0, 0};
    f1 = (wok && kk1 < Kd) ? *(const bf16x8*)&Wrow[kk1] : bf16x8{0, 0, 0, 0, 0, 0, 0, 0};
  };

  // prologue
  xload(0);
  wload(0, wcur0, wcur1);
  xwrite(0);
  __syncthreads();

  for (int it = 0; it < KT; ++it) {
    int curb = it & 1;
    bool more = (it + 1 < KT);
    if (more) { xload((it + 1) * 64); wload((it + 1) * 64, wnxt0, wnxt1); }
    #pragma unroll
    for (int nt = 0; nt < LT / 16; nt++) {
      bf16x8 bx0 = *(bf16x8*)&Xt[curb * XSZ + (nt * 16 + col) * 72 + quad * 8];
      acc[nt] = __builtin_amdgcn_mfma_f32_16x16x32_bf16(wcur0, bx0, acc[nt], 0, 0, 0);
      bf16x8 bx1 = *(bf16x8*)&Xt[curb * XSZ + (nt * 16 + col) * 72 + 32 + quad * 8];
      acc[nt] = __builtin_amdgcn_mfma_f32_16x16x32_bf16(wcur1, bx1, acc[nt], 0, 0, 0);
    }
    if (more) xwrite(curb ^ 1);
    __syncthreads();
    wcur0 = wnxt0; wcur1 = wnxt1;
  }

  // ---- epilogue ----
  int o_base = o0 + w * 16 + quad * 4;
  #pragma unroll
  for (int r = 0; r < 4; r++) {
    int o = o_base + r;
    bool ov = o < O;
    float bo = (bias && ov) ? bias[o] : 0.f;
    float ps = 0.f, pq = 0.f;
    #pragma unroll
    for (int nt = 0; nt < LT / 16; nt++) {
      int l = l0 + nt * 16 + col;
      float v = acc[nt][r] + bo;
      if (flags & 1) v = gelu_f(v);
      v *= outmul;
      if (l >= L) v = 0.f;
      if (ov && l < L) {
        if (flags & 2) ((short*)Yv)[(size_t)b * ybs + (size_t)o * Ldy + l] = f2bf(v);
        else           ((float*)Yv)[kc * slice + (size_t)b * ybs + (size_t)o * Ldy + l] = v;
      }
      ps += v; pq += v * v;
    }
    if ((flags & 8) && ov) {
      ps += __shfl_xor(ps, 1); ps += __shfl_xor(ps, 2);
      ps += __shfl_xor(ps, 4); ps += __shfl_xor(ps, 8);
      pq += __shfl_xor(pq, 1); pq += __shfl_xor(pq, 2);
      pq += __shfl_xor(pq, 4); pq += __shfl_xor(pq, 8);
      if (col == 0) { atomicAdd(&osum[o], ps); atomicAdd(&osq[o], pq); }
    }
  }
}

// ---------------- generic GEMM wrapper (c1, c2) ----------------
template<int LT, bool XBF16>
__global__ __launch_bounds__(256) void k_gemm3(const short* __restrict__ Wbf,
                                               const void* __restrict__ Xv,
                                               void* __restrict__ Yv,
                                               const float* __restrict__ ssum,
                                               const float* __restrict__ ssq,
                                               const float* __restrict__ sg,
                                               const float* __restrict__ bias,
                                               float* __restrict__ osum, float* __restrict__ osq,
                                               int O, int Kd, int Kstride, int XLd, int Ldy,
                                               size_t xbs, size_t ybs,
                                               int flags, float outmul,
                                               int ksplit, size_t slice) {
  __shared__ __align__(16) short Xt[2][LT * 72];
  int kc = (int)blockIdx.y % ksplit;
  int o0 = ((int)blockIdx.y / ksplit) * 64;
  gemm_body<LT, XBF16>(Wbf, Xv, Yv, ssum, ssq, sg, bias, osum, osq,
                       O, Kd, Kstride, XLd, Ldy, xbs, ybs, flags, outmul,
                       kc, slice, o0, blockIdx.x * LT, blockIdx.z, &Xt[0][0]);
}

// ---------------- fused q + kv GEMM (one launch, block-uniform config) ----------------
// blockIdx.y 0..5: q (O=C2, out qbuf [o][L], *ATT_SCALE*LOG2E); 6..17: kv (O=C, out kvbuf [o][KVL])
__global__ __launch_bounds__(256) void k_gemm_qkv(const short* __restrict__ wq,
                                                  const short* __restrict__ wkv,
                                                  const short* __restrict__ x2,
                                                  const short* __restrict__ kvin,
                                                  short* __restrict__ qout,
                                                  short* __restrict__ kvout,
                                                  const float* __restrict__ qbias,
                                                  const float* __restrict__ kvbias) {
  __shared__ __align__(16) short Xt[2][128 * 72];
  int y = blockIdx.y;
  if (y < 6) {
    gemm_body<128, true>(wq, (const void*)x2, (void*)qout,
                         nullptr, nullptr, nullptr, qbias, nullptr, nullptr,
                         C2, C2, C2, C2, L, (size_t)C2 * L, (size_t)C2 * L,
                         2, ATT_SCALE * LOG2E, 0, 0,
                         y * 64, blockIdx.x * 128, blockIdx.z, &Xt[0][0]);
  } else {
    gemm_body<128, true>(wkv, (const void*)kvin, (void*)kvout,
                         nullptr, nullptr, nullptr, kvbias, nullptr, nullptr,
                         C, C2, C2, C2, KVL, (size_t)C2 * L, (size_t)C * KVL,
                         2, 1.0f, 0, 0,
                         (y - 6) * 64, blockIdx.x * 128, blockIdx.z, &Xt[0][0]);
  }
}

// ---------------- h2 finalize: sum 4 c1 partials + cb1, gelu, bn2 stats, write [l][96] ----------------
__global__ __launch_bounds__(256) void k_h2fin_t(const float* __restrict__ part,
                                                 const float* __restrict__ cb1,
                                                 float* __restrict__ h2,
                                                 float* __restrict__ sum, float* __restrict__ sq) {
  __shared__ float tile[96][33];
  __shared__ float lsum[96], lsq[96];
  constexpr size_t SL = (size_t)B * 96 * L;
  int b = blockIdx.y, l0 = blockIdx.x * 32;
  int t = threadIdx.x;
  #pragma unroll
  for (int p = 0; p < 12; p++) {
    int u = t + p * 256;
    int o = u >> 5, li = u & 31;
    int l = l0 + li;
    float v = 0.f;
    if (l < L) {
      size_t idx = ((size_t)b * 96 + o) * L + l;
      v = gelu_f(part[idx] + part[SL + idx] + part[2 * SL + idx] + part[3 * SL + idx] + cb1[o]);
    }
    tile[o][li] = v;
    float vs = v, vq = v * v;
    vs += __shfl_xor(vs, 1); vs += __shfl_xor(vs, 2); vs += __shfl_xor(vs, 4);
    vs += __shfl_xor(vs, 8); vs += __shfl_xor(vs, 16);
    vq += __shfl_xor(vq, 1); vq += __shfl_xor(vq, 2); vq += __shfl_xor(vq, 4);
    vq += __shfl_xor(vq, 8); vq += __shfl_xor(vq, 16);
    if ((t & 31) == 0) { lsum[o] = vs; lsq[o] = vq; }
  }
  __syncthreads();
  if (t < 96) { atomicAdd(&sum[t], lsum[t]); atomicAdd(&sq[t], lsq[t]); }
  #pragma unroll
  for (int p = 0; p < 12; p++) {
    int u = t + p * 256;
    int lr = u / 96, o = u % 96;
    int l = l0 + lr;
    if (l < L) h2[((size_t)b * L + l) * 96 + o] = tile[o][lr];
  }
}

// ---------------- MFMA flash attention: bf16 P in LDS (2x b128 PV reads), XCD-swizzled grid ----------------
__global__ __launch_bounds__(512, 4) void k_attn_mfma(const short* __restrict__ q,
                                                      const short* __restrict__ kv,
                                                      float* __restrict__ out) {
  __shared__ __align__(16) char smem[2 * 8192 + 2 * 6144 + 18432];  // 47104 B
  short* Ks0 = (short*)smem;
  short* Ks1 = (short*)(smem + 8192);
  short* Vf0 = (short*)(smem + 16384);
  short* Vf1 = (short*)(smem + 22528);
  short* PFh = (short*)(smem + 28672);   // 8 waves x 16 rows x 72 shorts (bf16 P)
  float* Os  = (float*)smem;

  // grid (64, 8): bh fastest -> XCD = bh % 8 = h; each XCD holds one head's Q+KV (L2-fits)
  int bh = blockIdx.x;
  int h = bh & 7, b = bh >> 3;
  int lt0 = blockIdx.y * 128;
  int t = threadIdx.x;
  int w = t >> 6, lane = t & 63;
  int col = lane & 15, quad = lane >> 4;
  const short* qb = q  + ((size_t)b * C2 + h * HD) * L;
  const short* kb = kv + ((size_t)b * C  + h * HD) * KVL;
  const short* vb = kv + ((size_t)b * C + C2 + h * HD) * KVL;

  bf16x8 aq0, aq1;
  {
    int l = lt0 + w * 16 + col;
    bool ok = l < L;
    const short* qp = qb + (size_t)(quad * 8) * L + l;
    short v0[8];
    #pragma unroll
    for (int jj = 0; jj < 8; jj++) v0[jj] = ok ? qp[(size_t)jj * L] : (short)0;
    aq0 = *(bf16x8*)v0;
    if (quad < 2) {
      const short* qp1 = qb + (size_t)(32 + quad * 8) * L + l;
      short v1[8];
      #pragma unroll
      for (int jj = 0; jj < 8; jj++) v1[jj] = ok ? qp1[(size_t)jj * L] : (short)0;
      aq1 = *(bf16x8*)v1;
    } else {
      aq1 = bf16x8{0, 0, 0, 0, 0, 0, 0, 0};
    }
  }

  short kreg[8];
  bf16x8 vreg;

  auto stage_load = [&](int m0) {
    if (t < 384) {
      int m = t & 63, j = t >> 6;
      int gm = m0 + m;
      bool ok = gm < L;
      const short* src = kb + (size_t)(8 * j) * KVL + gm;
      #pragma unroll
      for (int jj = 0; jj < 8; jj++) kreg[jj] = ok ? src[(size_t)jj * KVL] : (short)0;
    }
    if (t >= 128) {
      int a = t - 128;
      int d = (a & 7) | ((a >> 6) << 3);
      int o = (a >> 3) & 7;
      int mb = m0 + o * 8;
      const short* src = vb + (size_t)d * KVL + mb;
      if (mb + 8 <= L) {
        vreg = *(const bf16x8*)src;
      } else {
        short tmp[8];
        #pragma unroll
        for (int j = 0; j < 8; j++) tmp[j] = (mb + j < L) ? src[j] : (short)0;
        vreg = *(bf16x8*)tmp;
      }
    }
  };
  auto stage_write = [&](short* Kd, short* Vd) {
    if (t < 384) {
      int m = t & 63, j = t >> 6;
      int slot = ((m >> 4) * 2 + (j >> 2)) * 64 + (j & 3) * 16 + (m & 15);
      *(bf16x8*)&Kd[slot * 8] = *(bf16x8*)kreg;
    }
    if (t >= 128) {
      int a = t - 128;
      int d = (a & 7) | ((a >> 6) << 3);
      int o = (a >> 3) & 7;
      int lanep = ((o & 3) << 4) | (d & 15);
      *(bf16x8*)&Vd[(((o >> 2) * 3 + (d >> 4)) * 64 + lanep) * 8] = vreg;
    }
  };

  if (t < 256) {
    int i = t & 127;
    int ms = i >> 5, qq = 2 + ((i >> 4) & 1), cc = i & 15;
    int slot = (ms * 2 + 1) * 64 + qq * 16 + cc;
    short* Kd = (t < 128) ? Ks0 : Ks1;
    *(bf16x8*)&Kd[slot * 8] = bf16x8{0, 0, 0, 0, 0, 0, 0, 0};
  }

  stage_load(0);
  stage_write(Ks0, Vf0);

  floatx4 of[3];
  #pragma unroll
  for (int i = 0; i < 3; i++) of[i] = floatx4{0.f, 0.f, 0.f, 0.f};
  float rs[4] = {0.f, 0.f, 0.f, 0.f};
  __syncthreads();

  for (int it = 0; it < 16; ++it) {
    int m0 = it * 64;
    short* Kc = (it & 1) ? Ks1 : Ks0;
    short* Vc = (it & 1) ? Vf1 : Vf0;
    short* Kn = (it & 1) ? Ks0 : Ks1;
    short* Vn = (it & 1) ? Vf0 : Vf1;
    if (it < 15) stage_load(m0 + 64);

    // ---- QK^T (conflict-free lane-contiguous b128 reads) ----
    floatx4 sf[4];
    __builtin_amdgcn_s_setprio(1);
    #pragma unroll
    for (int ms = 0; ms < 4; ms++) {
      bf16x8 bk0 = *(bf16x8*)&Kc[((ms * 2 + 0) * 64 + lane) * 8];
      bf16x8 bk1 = *(bf16x8*)&Kc[((ms * 2 + 1) * 64 + lane) * 8];
      floatx4 a4 = floatx4{0.f, 0.f, 0.f, 0.f};
      a4 = __builtin_amdgcn_mfma_f32_16x16x32_bf16(aq0, bk0, a4, 0, 0, 0);
      a4 = __builtin_amdgcn_mfma_f32_16x16x32_bf16(aq1, bk1, a4, 0, 0, 0);
      sf[ms] = a4;
    }
    __builtin_amdgcn_s_setprio(0);

    // ---- exp2 -> PFh (bf16, RNE same as old pack8; wave-private, no barrier) ----
    // value at row (ms*4+r), col lane: S-row = w*16+quad*4+r, m-col = m0+ms*16+col
    short* pwh = PFh + w * 1152 + lane;
    #pragma unroll
    for (int ms = 0; ms < 4; ms++) {
      int m = m0 + ms * 16 + col;
      bool ok = m < L;
      #pragma unroll
      for (int r = 0; r < 4; r++) {
        float e = ok ? exp2_hw(sf[ms][r]) : 0.f;
        rs[r] += e;                      // full-precision row-sum (unchanged)
        pwh[(ms * 4 + r) * 72] = f2bf(e);
      }
    }

    // ---- PV: one aligned b128 read per mh (banks <=2-way = free) ----
    __builtin_amdgcn_s_setprio(1);
    #pragma unroll
    for (int mh = 0; mh < 2; mh++) {
      int prow = (col & 3) + 4 * (mh * 2 + (quad >> 1));
      int pcol = (col >> 2) * 16 + (quad & 1) * 8;
      bf16x8 ap = *(bf16x8*)&PFh[w * 1152 + prow * 72 + pcol];
      #pragma unroll
      for (int ds = 0; ds < 3; ds++) {
        bf16x8 bv = *(bf16x8*)&Vc[((mh * 3 + ds) * 64 + lane) * 8];
        of[ds] = __builtin_amdgcn_mfma_f32_16x16x32_bf16(ap, bv, of[ds], 0, 0, 0);
      }
    }
    __builtin_amdgcn_s_setprio(0);
    if (it < 15) stage_write(Kn, Vn);
    __syncthreads();
  }

  #pragma unroll
  for (int r = 0; r < 4; r++) {
    float v = rs[r];
    v += __shfl_xor(v, 1); v += __shfl_xor(v, 2);
    v += __shfl_xor(v, 4); v += __shfl_xor(v, 8);
    rs[r] = v;
  }
  #pragma unroll
  for (int r = 0; r < 4; r++) {
    float inv = 1.f / rs[r];
    #pragma unroll
    for (int ds = 0; ds < 3; ds++)
      Os[(ds * 16 + col) * 130 + w * 16 + quad * 4 + r] = of[ds][r] * inv;
  }
  __syncthreads();
  for (int i = t; i < 48 * 128; i += 512) {
    int d = i >> 7, ll = i & 127;
    int l = lt0 + ll;
    if (l < L) out[((size_t)b * C2 + h * HD + d) * L + l] = Os[d * 130 + ll];
  }
}

// ---------------- projection dw3 + gelu -> t1 [l][C], bn1 stats ----------------
__global__ __launch_bounds__(256) void k_dwproj_t(const float* __restrict__ xt2,
                                                  const float* __restrict__ ao,
                                                  const float* __restrict__ dww,
                                                  const float* __restrict__ dwb,
                                                  float* __restrict__ t1,
                                                  float* __restrict__ sum, float* __restrict__ sq) {
  __shared__ float tile[32][67];
  __shared__ float rs[4][32], rq[4][32];
  int b = blockIdx.z, c0 = blockIdx.y * 32, l0 = blockIdx.x * 64;
  int t = threadIdx.x;
  if (c0 < C2) {
    for (int u = t; u < 32 * 66; u += 256) {
      int cc = u / 66, li = u % 66;
      int l = l0 - 1 + li;
      tile[cc][li] = (l >= 0 && l < L) ? xt2[((size_t)b * C + c0 + cc) * L + l] : 0.f;
    }
  } else {
    for (int u = t; u < 32 * 66; u += 256) {
      int li = u >> 5, cc = u & 31;
      int l = l0 - 1 + li;
      tile[cc][li] = (l >= 0 && l < L) ? ao[((size_t)b * L + l) * C2 + (c0 - C2 + cc)] : 0.f;
    }
  }
  __syncthreads();
  int c = c0 + (t & 31);
  float w0 = dww[c * 3], w1 = dww[c * 3 + 1], w2 = dww[c * 3 + 2], bb = dwb[c];
  int cc = t & 31;
  float s = 0.f, s2 = 0.f;
  #pragma unroll
  for (int p = 0; p < 8; p++) {
    int lr = (t >> 5) + p * 8;
    int l = l0 + lr;
    float v = 0.f;
    if (l < L) {
      v = gelu_f(tile[cc][lr] * w0 + tile[cc][lr + 1] * w1 + tile[cc][lr + 2] * w2 + bb);
      t1[((size_t)b * L + l) * C + c] = v;
    }
    s += v; s2 += v * v;
  }
  s += __shfl_xor(s, 32, 64); s2 += __shfl_xor(s2, 32, 64);
  int wv = t >> 6, ln = t & 63;
  if (ln < 32) { rs[wv][ln] = s; rq[wv][ln] = s2; }
  __syncthreads();
  if (t < 32) {
    float a = rs[0][t] + rs[1][t] + rs[2][t] + rs[3][t];
    float qq = rq[0][t] + rq[1][t] + rq[2][t] + rq[3][t];
    atomicAdd(&sum[c0 + t], a);
    atomicAdd(&sq[c0 + t], qq);
  }
}

// ---------------- final: out[b,l,c] = bn3(y3) + residual, bn3 inlined from sums ----------------
__global__ void k_final(const float* __restrict__ y3, const float* __restrict__ xt2,
                        const float* __restrict__ ao,
                        const float* __restrict__ sum3, const float* __restrict__ sq3,
                        const float* __restrict__ bn3g, const float* __restrict__ bn3b,
                        float* __restrict__ out) {
  __shared__ float tile[32][33];
  int b = blockIdx.z;
  int l0 = blockIdx.x * 32, c0 = blockIdx.y * 32;
  int tx = threadIdx.x, ty = threadIdx.y;
  #pragma unroll
  for (int i = 0; i < 4; i++) {
    int c = c0 + ty + i * 8, l = l0 + tx;
    if (l < L) {
      float m = sum3[c] * INV_N;
      float v = sq3[c] * INV_N - m * m;
      float sc = bn3g[c] * rsqrtf(v + BN_EPS);
      float dd = bn3b[c] - m * sc;
      size_t idx = ((size_t)b * C + c) * L + l;
      float val = y3[idx] * sc + dd;
      if (c < C2) val += xt2[idx];
      tile[ty + i * 8][tx] = val;
    }
  }
  __syncthreads();
  #pragma unroll
  for (int i = 0; i < 4; i++) {
    int l = l0 + ty + i * 8, c = c0 + tx;
    if (l < L) {
      float val = tile[tx][ty + i * 8];
      if (c >= C2) val += ao[((size_t)b * L + l) * C2 + (c - C2)];
      out[((size_t)b * L + l) * C + c] = val;
    }
  }
}

extern "C" void kernel_launch(void* const* d_in, const int* in_sizes, int n_in,
                              void* d_out, int out_size, void* d_ws, size_t ws_size,
                              hipStream_t stream) {
  const float* x    = (const float*)d_in[0];
  const float* dcw  = (const float*)d_in[1];
  const float* dcb  = (const float*)d_in[2];
  const float* p1w  = (const float*)d_in[3];
  const float* p1b  = (const float*)d_in[4];
  const float* p2w  = (const float*)d_in[5];
  const float* p2b  = (const float*)d_in[6];
  const float* qw   = (const float*)d_in[7];
  const float* qb   = (const float*)d_in[8];
  const float* kvw  = (const float*)d_in[9];
  const float* kvb  = (const float*)d_in[10];
  const float* lcw  = (const float*)d_in[11];
  const float* lcb  = (const float*)d_in[12];
  const float* dww  = (const float*)d_in[13];
  const float* dwb  = (const float*)d_in[14];
  const float* bn1g = (const float*)d_in[15];
  const float* bn1b = (const float*)d_in[16];
  const float* c1w  = (const float*)d_in[17];
  const float* c1b  = (const float*)d_in[18];
  const float* bn2g = (const float*)d_in[19];
  const float* bn2b = (const float*)d_in[20];
  const float* c2w  = (const float*)d_in[21];
  const float* c2b  = (const float*)d_in[22];
  const float* bn3g = (const float*)d_in[23];
  const float* bn3b = (const float*)d_in[24];
  float* out = (float*)d_out;
  float* ws  = (float*)d_ws;

  float* xt      = ws + OFF_XT;                      // fp32 [c][l], later t1 [l][C]
  float* xt2     = ws + OFF_XT2;                     // fp32 [c][l] lower half only
  short* kvbuf   = (short*)(ws + OFF_KV);            // bf16 kv [o][KVL]
  float* c1part  = ws + OFF_KV;                      // fp32 4 slices (kvbuf dead after attn)
  float* y3      = ws + OFF_KV;                      // fp32 (c1part dead after h2fin)
  short* x2bf    = (short*)(ws + OFF_AX);            // bf16 x2 [l][c]
  short* kvinbf  = (short*)(ws + OFF_AX + SZ_HALF / 2);  // bf16 kv_in [l][c]
  float* attnout = ws + OFF_AX;                      // fp32, live until k_final
  short* qbuf    = (short*)(ws + OFF_Q);             // bf16 q [o][l]
  float* h2      = ws + OFF_Q;                       // fp32 [l][96] (reuse)
  float* sm      = ws + OFF_SM;

  float* pooled = sm + SM_POOLED;
  float* xm     = sm + SM_XM;
  float* wdyn   = sm + SM_WDYN;
  float* bdyn   = sm + SM_BDYN;
  float* sum1 = sm + SM_SUM1; float* sq1 = sm + SM_SQ1;
  float* cb1 = sm + SM_CB1;
  float* sum2 = sm + SM_SUM2; float* sq2 = sm + SM_SQ2;
  float* cb2 = sm + SM_CB2;
  float* sum3 = sm + SM_SUM3; float* sq3 = sm + SM_SQ3;
  short* wqbf  = (short*)(sm + SM_WQ);
  short* wkvbf = (short*)(sm + SM_WKV);
  short* wc1bf = (short*)(sm + SM_WC1);
  short* wc2bf = (short*)(sm + SM_WC2);

  hipMemsetAsync((void*)(sm + SM_SUM1), 0, (SM_ZEND - SM_SUM1) * sizeof(float), stream);

  dim3 tb32(32, 8);
  // 0. fused prep (weights + cb1/cb2) + input transpose (R7-measured 256-thread form)
  k_pre_t<<<3362, tb32, 0, stream>>>(qw, wqbf, kvw, wkvbf, c1w, wc1bf, c2w, wc2bf,
                                     c1b, bn1b, c2b, bn2b, cb1, cb2, x, xt);
  // 0b. x2bf + kv_in in [l][c] layout, straight from x
  k_kvin<<<dim3(125, B), 384, 0, stream>>>(x, lcw, lcb, x2bf, kvinbf);
  // 1. pooled / mean
  k_pool<<<dim3(C2, B), 256, 0, stream>>>(xt, pooled, xm);
  // 2. fused tiny MLP (mlp1 + mix2, h1 in LDS)
  k_mlp_mix<<<dim3(4, B), 384, 0, stream>>>(pooled, xm, p1w, p1b, p2w, p2b, dcw, dcb, wdyn, bdyn);
  // 3. dyn-conv -> xt2 lower
  k_dwconv<<<dim3(C2, B), 256, 0, stream>>>(xt, wdyn, bdyn, xt2);
  // 4. fused q + kv GEMM (one launch, 1152 blocks)
  k_gemm_qkv<<<dim3(8, 18, B), 256, 0, stream>>>(wqbf, wkvbf, x2bf, kvinbf,
                                                 qbuf, kvbuf, qb, kvb);
  // 5. MFMA flash attention -> attnout (XCD-swizzled grid, bf16 P in LDS)
  k_attn_mfma<<<dim3(64, 8), 512, 0, stream>>>(qbuf, kvbuf, attnout);
  // 6. projection dw3+gelu -> t1 [l][C] (reads xt2 lower + ao upper), bn1 stats
  k_dwproj_t<<<dim3(16, 24, B), 256, 0, stream>>>(xt2, attnout, dww, dwb, xt, sum1, sq1);
  // 7. c1 GEMM, K-split x4, BN1 inlined from sums -> c1part (in dead kvbuf region)
  k_gemm3<128, false><<<dim3(8, 8, B), 256, 0, stream>>>(
      wc1bf, (const void*)xt, (void*)c1part, sum1, sq1, bn1g, nullptr, nullptr, nullptr,
      96, 192, C, C, L, (size_t)C * L, (size_t)96 * L, 0, 1.0f, 4, (size_t)B * 96 * L);
  // 7b. h2 = gelu(sum partials + cb1) -> [l][96], bn2 stats
  k_h2fin_t<<<dim3(32, B), 256, 0, stream>>>(c1part, cb1, h2, sum2, sq2);
  // 8. c2 GEMM, BN2 inlined from sums, fp32 out y3, bn3 stats
  k_gemm3<128, false><<<dim3(8, 12, B), 256, 0, stream>>>(
      wc2bf, (const void*)h2, (void*)y3, sum2, sq2, bn2g, cb2, sum3, sq3,
      C, 96, 96, 96, L, (size_t)96 * L, (size_t)C * L, 8, 1.0f, 1, 0);
  // 9. final: bn3 (inlined) + residual (xt2 lower / ao upper) + transpose back
  k_final<<<dim3(32, 24, B), tb32, 0, stream>>>(y3, xt2, attnout, sum3, sq3, bn3g, bn3b, out);
}